// Round 1
// baseline (56.912 us; speedup 1.0000x reference)
//
#include <hip/hip_runtime.h>

#define RTOL_F 0.3f

__global__ __launch_bounds__(256) void regp_pool_kernel(
    const float* __restrict__ x, float* __restrict__ out, int total) {
    int idx = blockIdx.x * blockDim.x + threadIdx.x;
    if (idx >= total) return;

    const int j  = idx & 127;          // Wo = 128
    const int i  = (idx >> 7) & 127;   // Ho = 128
    const int bc = idx >> 14;          // B*C = 512
    const float* __restrict__ src = x + (size_t)bc * (130 * 130) + i * 130 + j;

    // 3x3 window: win[a][b] = x[bc, i+a, j+b]
    float win[3][3];
#pragma unroll
    for (int a = 0; a < 3; ++a)
#pragma unroll
        for (int b = 0; b < 3; ++b)
            win[a][b] = src[a * 130 + b];

    float p = 0.0f, mc = 0.0f;
#pragma unroll
    for (int ni = 0; ni < 3; ++ni) {
#pragma unroll
        for (int nj = 0; nj < 3; ++nj) {
            const float c = win[ni][nj];
            const float t = RTOL_F * fabsf(c);
            float cnt = -1.0f;          // subtract self
            int npad = 9;               // compile-time constant after unroll
#pragma unroll
            for (int di = -1; di <= 1; ++di) {
#pragma unroll
                for (int dj = -1; dj <= 1; ++dj) {
                    const int a = ni + di, b = nj + dj;
                    if (a >= 0 && a < 3 && b >= 0 && b < 3) {  // folds at compile time
                        cnt += (fabsf(win[a][b] - c) <= t) ? 1.0f : 0.0f;
                        npad--;
                    }
                }
            }
            // zero-padding cells are "close" iff c == 0 exactly
            if (c == 0.0f) cnt += (float)npad;

            // sequential update, replicating reference order exactly
            const bool  gt  = cnt > mc;
            const float pn  = gt ? c   : p;
            const float mcn = gt ? cnt : mc;
            p  = (cnt == mcn) ? (c + pn) * 0.5f : pn;
            mc = mcn;
        }
    }
    out[idx] = p;
}

extern "C" void kernel_launch(void* const* d_in, const int* in_sizes, int n_in,
                              void* d_out, int out_size, void* d_ws, size_t ws_size,
                              hipStream_t stream) {
    const float* x   = (const float*)d_in[0];
    float*       out = (float*)d_out;
    const int total  = out_size;  // 8*64*128*128 = 8388608
    const int threads = 256;
    const int blocks  = (total + threads - 1) / threads;
    regp_pool_kernel<<<blocks, threads, 0, stream>>>(x, out, total);
}

// Round 2
// 41.723 us; speedup vs baseline: 1.3641x; 1.3641x over previous
//
#include <hip/hip_runtime.h>

// RegpPooling2D: for each 3x3 window, each of the 9 candidates counts how many
// window cells are within 0.3*|c| of it (zero-padded cells count only when
// c==0 exactly); sequential argmax-with-tie-average picks the output.
//
// This version processes W=4 adjacent output pixels per thread on a 3x6 input
// tile, sharing closeness checks across the windows a candidate appears in.

#define W_T 4

__global__ __launch_bounds__(256) void regp_pool_kernel(
    const float* __restrict__ x, float* __restrict__ out) {
    const int tx = blockIdx.x * blockDim.x + threadIdx.x;
    // 512 (B*C) x 128 (i) x 32 (j-tiles)
    const int jt = tx & 31;
    const int i  = (tx >> 5) & 127;
    const int bc = tx >> 12;
    const int j  = jt * W_T;

    const float* __restrict__ src = x + (size_t)bc * (130 * 130) + i * 130 + j;

    // 3x6 input tile in registers
    float win[3][6];
#pragma unroll
    for (int rr = 0; rr < 3; ++rr) {
#pragma unroll
        for (int qq = 0; qq < 6; qq += 2) {
            const float2 v = *reinterpret_cast<const float2*>(src + rr * 130 + qq);
            win[rr][qq]     = v.x;
            win[rr][qq + 1] = v.y;
        }
    }

    // cnt[r][q][v]: count (already -1'd and pad-corrected) for candidate at
    // tile pos (r,q) playing role nj=v. Only valid (q,v) combos are written,
    // and all indexing is compile-time constant after unrolling.
    int cnt[3][6][3];

#pragma unroll
    for (int r = 0; r < 3; ++r) {
#pragma unroll
        for (int q = 0; q < 6; ++q) {
            const bool needR = (q <= 3);             // v=0 (nj=0): cols {q,q+1}
            const bool needA = (q >= 1 && q <= 4);   // v=1 (nj=1): cols {q-1..q+1}
            const bool needL = (q >= 2);             // v=2 (nj=2): cols {q-1,q}

            const float c = win[r][q];
            const float t = 0.3f * fabsf(c);

            // per-neighbor-row partial sums over the 3 col variants
            int sl[3], sa[3], sr_[3];
#pragma unroll
            for (int rr = 0; rr < 3; ++rr) {
                if (rr < r - 1 || rr > r + 1) continue;  // rows this ni-role uses
                const int bl = (q > 0 && (needL || needA))
                                   ? (int)(fabsf(win[rr][q - 1] - c) <= t) : 0;
                const int bm = (int)(fabsf(win[rr][q] - c) <= t);
                const int br = (q < 5 && (needR || needA))
                                   ? (int)(fabsf(win[rr][q + 1] - c) <= t) : 0;
                if (needR || needA) sr_[rr] = bm + br;
                if (needL)          sl[rr]  = bl + bm;
                if (needA)          sa[rr]  = bl + bm + br;
            }

            // combine rows (role ni = r uses rows [r-1, r+1] clipped to [0,2]);
            // start from -1 to subtract the self-match.
            int cr = -1, ca = -1, cl = -1;
#pragma unroll
            for (int rr = 0; rr < 3; ++rr) {
                if (rr < r - 1 || rr > r + 1) continue;
                if (needR) cr += sr_[rr];
                if (needA) ca += sa[rr];
                if (needL) cl += sl[rr];
            }

            // zero-padded cells are "close" iff c == 0 exactly
            const bool zc = (c == 0.0f);
            if (needR) { const int np = (r == 1) ? 3 : 5; cnt[r][q][0] = cr + (zc ? np : 0); }
            if (needA) { const int np = (r == 1) ? 0 : 3; cnt[r][q][1] = ca + (zc ? np : 0); }
            if (needL) { const int np = (r == 1) ? 3 : 5; cnt[r][q][2] = cl + (zc ? np : 0); }
        }
    }

    // selection: reference order is ni outer, nj inner, sequential update
    float res[W_T];
#pragma unroll
    for (int w = 0; w < W_T; ++w) {
        float p = 0.0f;
        int   mc = 0;
#pragma unroll
        for (int r = 0; r < 3; ++r) {
#pragma unroll
            for (int nj = 0; nj < 3; ++nj) {
                const int   q  = w + nj;
                const float c  = win[r][q];
                const int   cv = cnt[r][q][nj];
                const bool  gt = cv > mc;
                const float pn = gt ? c : p;
                const int  mcn = gt ? cv : mc;
                p  = (cv == mcn) ? (c + pn) * 0.5f : pn;
                mc = mcn;
            }
        }
        res[w] = p;
    }

    // coalesced float4 store (base index is a multiple of 4)
    float4 o;
    o.x = res[0]; o.y = res[1]; o.z = res[2]; o.w = res[3];
    *reinterpret_cast<float4*>(out + (size_t)(tx) * W_T) = o;
}

extern "C" void kernel_launch(void* const* d_in, const int* in_sizes, int n_in,
                              void* d_out, int out_size, void* d_ws, size_t ws_size,
                              hipStream_t stream) {
    const float* x   = (const float*)d_in[0];
    float*       out = (float*)d_out;
    // 8*64*128*128 / 4 pixels per thread = 2,097,152 threads
    const int threads = 256;
    const int blocks  = (out_size / W_T + threads - 1) / threads;
    regp_pool_kernel<<<blocks, threads, 0, stream>>>(x, out);
}

// Round 3
// 35.933 us; speedup vs baseline: 1.5839x; 1.1611x over previous
//
#include <hip/hip_runtime.h>

// RegpPooling2D: for each 3x3 window, each of the 9 candidates counts how many
// window cells are within 0.3*|c| of it (zero-padded cells count only when
// c==0 exactly); sequential argmax-with-tie-average picks the output.
//
// W_T=8 output pixels per thread on a 3x10 input tile; each ordered
// (candidate, neighbor) pair is checked exactly once per tile; the self-check
// is constant-folded (always true, cancels the -1).

#define W_T 8
#define QC (W_T + 2)   // tile columns

__global__ __launch_bounds__(256) void regp_pool_kernel(
    const float* __restrict__ x, float* __restrict__ out) {
    const int tx = blockIdx.x * blockDim.x + threadIdx.x;
    // 512 (B*C) x 128 (i) x 16 (j-tiles of 8)
    const int jt = tx & 15;
    const int i  = (tx >> 4) & 127;
    const int bc = tx >> 11;
    const int j  = jt * W_T;

    const float* __restrict__ src = x + (size_t)bc * (130 * 130) + i * 130 + j;

    // 3 x QC input tile in registers (float2 loads: rows are 8B-aligned)
    float win[3][QC];
#pragma unroll
    for (int rr = 0; rr < 3; ++rr) {
#pragma unroll
        for (int qq = 0; qq < QC; qq += 2) {
            const float2 v = *reinterpret_cast<const float2*>(src + rr * 130 + qq);
            win[rr][qq]     = v.x;
            win[rr][qq + 1] = v.y;
        }
    }

    // cnt[r][q][v]: pad-corrected count for candidate at tile (r,q) in role
    // nj=v. Only valid combos written; indices compile-time after unroll.
    int cnt[3][QC][3];

#pragma unroll
    for (int r = 0; r < 3; ++r) {
#pragma unroll
        for (int q = 0; q < QC; ++q) {
            const bool needR = (q <= W_T - 1);           // nj=0: cols {q, q+1}
            const bool needA = (q >= 1 && q <= W_T);     // nj=1: cols {q-1..q+1}
            const bool needL = (q >= 2);                 // nj=2: cols {q-1, q}

            const float c = win[r][q];
            const float t = 0.3f * fabsf(c);

            // per-neighbor-row partial sums over the 3 col variants
            int sl[3], sa[3], sr_[3];
#pragma unroll
            for (int rr = 0; rr < 3; ++rr) {
                if (rr < r - 1 || rr > r + 1) continue;  // rows this ni uses
                const int bl = (q > 0 && (needL || needA))
                                   ? (int)(fabsf(win[rr][q - 1] - c) <= t) : 0;
                // self-check is always true -> constant-folds, cancels the -1
                const int bm = (rr == r)
                                   ? 1
                                   : (int)(fabsf(win[rr][q] - c) <= t);
                const int br = (q < QC - 1 && (needR || needA))
                                   ? (int)(fabsf(win[rr][q + 1] - c) <= t) : 0;
                if (needR || needA) sr_[rr] = bm + br;
                if (needL)          sl[rr]  = bl + bm;
                if (needA)          sa[rr]  = bl + bm + br;
            }

            // combine rows (ni = r uses rows [r-1, r+1] clipped); -1 = self
            int cr = -1, ca = -1, cl = -1;
#pragma unroll
            for (int rr = 0; rr < 3; ++rr) {
                if (rr < r - 1 || rr > r + 1) continue;
                if (needR) cr += sr_[rr];
                if (needA) ca += sa[rr];
                if (needL) cl += sl[rr];
            }

            // zero-padded cells are "close" iff c == 0 exactly
            const int zb = (c == 0.0f) ? 1 : 0;
            if (needR) { const int np = (r == 1) ? 3 : 5; cnt[r][q][0] = cr + np * zb; }
            if (needA) { const int np = (r == 1) ? 0 : 3; cnt[r][q][1] = ca + np * zb; }
            if (needL) { const int np = (r == 1) ? 3 : 5; cnt[r][q][2] = cl + np * zb; }
        }
    }

    // selection: reference order is ni outer, nj inner, sequential update
    float res[W_T];
#pragma unroll
    for (int w = 0; w < W_T; ++w) {
        float p = 0.0f;
        int   mc = 0;
#pragma unroll
        for (int r = 0; r < 3; ++r) {
#pragma unroll
            for (int nj = 0; nj < 3; ++nj) {
                const int   q  = w + nj;
                const float c  = win[r][q];
                const int   cv = cnt[r][q][nj];
                const bool  gt = cv > mc;
                const float pn = gt ? c : p;
                const int  mcn = gt ? cv : mc;
                p  = (cv == mcn) ? (c + pn) * 0.5f : pn;
                mc = mcn;
            }
        }
        res[w] = p;
    }

    // two coalesced float4 stores (base is a multiple of 8 floats = 32B)
    float4 o0, o1;
    o0.x = res[0]; o0.y = res[1]; o0.z = res[2]; o0.w = res[3];
    o1.x = res[4]; o1.y = res[5]; o1.z = res[6]; o1.w = res[7];
    float* op = out + (size_t)tx * W_T;
    *reinterpret_cast<float4*>(op)     = o0;
    *reinterpret_cast<float4*>(op + 4) = o1;
}

extern "C" void kernel_launch(void* const* d_in, const int* in_sizes, int n_in,
                              void* d_out, int out_size, void* d_ws, size_t ws_size,
                              hipStream_t stream) {
    const float* x   = (const float*)d_in[0];
    float*       out = (float*)d_out;
    const int threads = 256;
    const int blocks  = (out_size / W_T + threads - 1) / threads;  // 4096
    regp_pool_kernel<<<blocks, threads, 0, stream>>>(x, out);
}

// Round 4
// 32.449 us; speedup vs baseline: 1.7539x; 1.1074x over previous
//
#include <hip/hip_runtime.h>

// RegpPooling2D, 2D-tiled: 2 output rows x 8 cols per thread on a 4x10 input
// tile. Each (candidate cell, neighbor cell) closeness check is computed once
// and shared across every window it appears in (up to 2 vertical x 3
// horizontal). Counts are applied to per-pixel selection state immediately in
// reference (ni,nj) order, so no count arrays are materialized.

#define W_T 8
#define QC (W_T + 2)

__global__ __launch_bounds__(256) void regp_pool_kernel(
    const float* __restrict__ x, float* __restrict__ out) {
    const int tx = blockIdx.x * blockDim.x + threadIdx.x;
    const int jt = tx & 15;          // 16 col-tiles of 8
    const int it = (tx >> 4) & 63;   // 64 row-pairs
    const int bc = tx >> 10;         // 512 B*C
    const int i  = it * 2;
    const int j  = jt * W_T;

    const float* __restrict__ src = x + (size_t)bc * (130 * 130) + i * 130 + j;

    // 4 x 10 input tile in registers
    float win[4][QC];
#pragma unroll
    for (int rr = 0; rr < 4; ++rr) {
#pragma unroll
        for (int qq = 0; qq < QC; qq += 2) {
            const float2 v = *reinterpret_cast<const float2*>(src + rr * 130 + qq);
            win[rr][qq]     = v.x;
            win[rr][qq + 1] = v.y;
        }
    }

    // selection state: window-row 0 (output row i) and 1 (output row i+1)
    float p[2][W_T];
    int   mc[2][W_T];
#pragma unroll
    for (int w = 0; w < W_T; ++w) {
        p[0][w] = 0.0f; p[1][w] = 0.0f;
        mc[0][w] = 0;   mc[1][w] = 0;
    }

    // sequential update, replicating reference order exactly
    auto upd = [](float& pp, int& mm, float c, int cv) {
        const bool  gt  = cv > mm;
        const float pn  = gt ? c : pp;
        const int   mcn = gt ? cv : mm;
        pp = (cv == mcn) ? (c + pn) * 0.5f : pn;
        mm = mcn;
    };

#pragma unroll
    for (int a = 0; a < 4; ++a) {            // candidate tile row
#pragma unroll
        for (int q = 0; q < QC; ++q) {       // candidate tile col
            const float c = win[a][q];
            const float t = 0.3f * fabsf(c);
            const bool needR = (q <= W_T - 1);        // nj=0 valid
            const bool needA = (q >= 1 && q <= W_T);  // nj=1 valid
            const bool needL = (q >= 2);              // nj=2 valid

            // s[v][da+1]: column sums for variant v at neighbor row a+da
            // v=0 (nj=0): cols {q,q+1}; v=1: {q-1..q+1}; v=2: {q-1,q}
            int s[3][3];
#pragma unroll
            for (int da = -1; da <= 1; ++da) {
                const int a2 = a + da;
                if (a2 < 0 || a2 > 3) continue;
                // neighbor-row usage by this candidate's roles:
                // W0: ni=a (a<=2), W1: ni=a-1 (a>=1);
                // rows(ni=0)={0,+1}, rows(1)={-1..+1}, rows(2)={-1,0}
                const bool useW0 = (a <= 2) && (a == 1 || (a == 0 ? (da >= 0) : (da <= 0)));
                const bool useW1 = (a >= 1) && (a == 2 || (a == 1 ? (da >= 0) : (da <= 0)));
                if (!(useW0 || useW1)) continue;
                const int bl = (needA || needL)
                                   ? (int)(fabsf(win[a2][q - 1] - c) <= t) : 0;
                // self-check always true -> folds
                const int bm = (da == 0) ? 1
                                         : (int)(fabsf(win[a2][q] - c) <= t);
                const int br = (needA || needR)
                                   ? (int)(fabsf(win[a2][q + 1] - c) <= t) : 0;
                if (needR) s[0][da + 1] = bm + br;
                if (needA) s[1][da + 1] = bl + bm + br;
                if (needL) s[2][da + 1] = bl + bm;
            }

            // pad correction: count = S - 1 + np*(c==0); np: 0/3/5
            const bool zc = (c == 0.0f);
            const int corr3 = zc ? 2 : -1;   // 3*zb - 1
            const int corr5 = zc ? 4 : -1;   // 5*zb - 1

#pragma unroll
            for (int nj = 0; nj < 3; ++nj) {
                const bool valid = (nj == 0) ? needR : (nj == 1) ? needA : needL;
                if (!valid) continue;
                const int px = q - nj;       // target output pixel column

                if (a == 0) {
                    // W0, ni=0: rows {0,1}
                    const int S = s[nj][1] + s[nj][2];
                    upd(p[0][px], mc[0][px], c, S + ((nj == 1) ? corr3 : corr5));
                } else if (a == 1) {
                    const int T = s[nj][1] + s[nj][2];         // abs rows {1,2}
                    // W0, ni=1: rows {0,1,2}
                    upd(p[0][px], mc[0][px], c,
                        T + s[nj][0] + ((nj == 1) ? -1 : corr3));
                    // W1, ni=0: rows {1,2}
                    upd(p[1][px], mc[1][px], c, T + ((nj == 1) ? corr3 : corr5));
                } else if (a == 2) {
                    const int T = s[nj][0] + s[nj][1];         // abs rows {1,2}
                    // W0, ni=2: rows {1,2}
                    upd(p[0][px], mc[0][px], c, T + ((nj == 1) ? corr3 : corr5));
                    // W1, ni=1: rows {1,2,3}
                    upd(p[1][px], mc[1][px], c,
                        T + s[nj][2] + ((nj == 1) ? -1 : corr3));
                } else {  // a == 3
                    // W1, ni=2: rows {2,3}
                    const int S = s[nj][0] + s[nj][1];
                    upd(p[1][px], mc[1][px], c, S + ((nj == 1) ? corr3 : corr5));
                }
            }
        }
    }

    // coalesced float4 stores, two output rows
    float* dst = out + (size_t)bc * (128 * 128) + i * 128 + j;
#pragma unroll
    for (int r2 = 0; r2 < 2; ++r2) {
        float4 oa, ob;
        oa.x = p[r2][0]; oa.y = p[r2][1]; oa.z = p[r2][2]; oa.w = p[r2][3];
        ob.x = p[r2][4]; ob.y = p[r2][5]; ob.z = p[r2][6]; ob.w = p[r2][7];
        *reinterpret_cast<float4*>(dst + r2 * 128)     = oa;
        *reinterpret_cast<float4*>(dst + r2 * 128 + 4) = ob;
    }
}

extern "C" void kernel_launch(void* const* d_in, const int* in_sizes, int n_in,
                              void* d_out, int out_size, void* d_ws, size_t ws_size,
                              hipStream_t stream) {
    const float* x   = (const float*)d_in[0];
    float*       out = (float*)d_out;
    const int threads = 256;
    const int total_threads = out_size / (2 * W_T);   // 524288
    const int blocks  = total_threads / threads;      // 2048
    regp_pool_kernel<<<blocks, threads, 0, stream>>>(x, out);
}

// Round 5
// 31.193 us; speedup vs baseline: 1.8245x; 1.0403x over previous
//
#include <hip/hip_runtime.h>

// RegpPooling2D, row-streamed 2D tile: 4 output rows x 8 cols per thread on a
// 6x10 input tile. Candidate rows are swept top-to-bottom; each closeness
// check is computed once and shared across every window containing it (up to
// 3 vertical x 3 horizontal). Only 3 output-row states are live at any point;
// completed rows are stored immediately. Reference (ni,nj) update order per
// window is preserved exactly.

#define W_T 8
#define H_T 4
#define QC (W_T + 2)   // 10 tile cols
#define AR (H_T + 2)   // 6 tile rows

__global__ __launch_bounds__(256) void regp_pool_kernel(
    const float* __restrict__ x, float* __restrict__ out) {
    const int tx = blockIdx.x * blockDim.x + threadIdx.x;
    const int jt = tx & 15;          // 16 col-tiles of 8
    const int it = (tx >> 4) & 31;   // 32 row-tiles of 4
    const int bc = tx >> 9;          // 512 B*C
    const int i  = it * H_T;
    const int j  = jt * W_T;

    const float* __restrict__ src = x + (size_t)bc * (130 * 130) + i * 130 + j;
    float* __restrict__ dst = out + (size_t)bc * (128 * 128) + i * 128 + j;

    float win[AR][QC];
    // preload tile rows 0,1 (iteration a=0 needs rows a..a+1)
#pragma unroll
    for (int rr = 0; rr < 2; ++rr) {
#pragma unroll
        for (int qq = 0; qq < QC; qq += 2) {
            const float2 v = *reinterpret_cast<const float2*>(src + rr * 130 + qq);
            win[rr][qq]     = v.x;
            win[rr][qq + 1] = v.y;
        }
    }

    float p[H_T][W_T];
    int   mc[H_T][W_T];
#pragma unroll
    for (int r = 0; r < H_T; ++r)
#pragma unroll
        for (int w = 0; w < W_T; ++w) { p[r][w] = 0.0f; mc[r][w] = 0; }

    // sequential update, replicating reference order exactly
    auto upd = [](float& pp, int& mm, float c, int cv) {
        const bool  gt  = cv > mm;
        const float pn  = gt ? c : pp;
        const int   mcn = gt ? cv : mm;
        pp = (cv == mcn) ? (c + pn) * 0.5f : pn;
        mm = mcn;
    };

#pragma unroll
    for (int a = 0; a < AR; ++a) {   // candidate tile row
        // stream in tile row a+1 (needed by this iteration; rows 0,1 preloaded)
        if (a >= 1 && a + 1 < AR) {
#pragma unroll
            for (int qq = 0; qq < QC; qq += 2) {
                const float2 v =
                    *reinterpret_cast<const float2*>(src + (a + 1) * 130 + qq);
                win[a + 1][qq]     = v.x;
                win[a + 1][qq + 1] = v.y;
            }
        }

#pragma unroll
        for (int q = 0; q < QC; ++q) {   // candidate tile col
            const bool vR = (q <= W_T - 1);         // nj=0 valid (px=q)
            const bool vA = (q >= 1 && q <= W_T);   // nj=1 valid (px=q-1)
            const bool vL = (q >= 2);               // nj=2 valid (px=q-2)

            const float c = win[a][q];
            const float t = 0.3f * fabsf(c);
            const bool  zc = (c == 0.0f);
            const int corr3 = zc ? 2 : -1;   // 3*(c==0) - 1
            const int corr5 = zc ? 4 : -1;   // 5*(c==0) - 1

            // s[v][da+1]: column sums for nj-variant v at neighbor row a+da
            // v=0: cols {q,q+1}; v=1: {q-1..q+1}; v=2: {q-1,q}
            int s[3][3];
#pragma unroll
            for (int da = -1; da <= 1; ++da) {
                if (da == -1 && a < 1) continue;       // no role uses row a-1
                if (da ==  1 && a > H_T) continue;     // no role uses row a+1
                const int a2 = a + da;                 // in [0, AR-1] by above
                const int bl = (q >= 1 && (vA || vL))
                                   ? (int)(fabsf(win[a2][q - 1] - c) <= t) : 0;
                // self-check always true -> constant-folds
                const int bm = (da == 0) ? 1
                                         : (int)(fabsf(win[a2][q] - c) <= t);
                const int br = (q <= QC - 2 && (vR || vA))
                                   ? (int)(fabsf(win[a2][q + 1] - c) <= t) : 0;
                if (vR) s[0][da + 1] = bm + br;
                if (vA) s[1][da + 1] = bl + bm + br;
                if (vL) s[2][da + 1] = bl + bm;
            }

#pragma unroll
            for (int nj = 0; nj < 3; ++nj) {
                const bool vv = (nj == 0) ? vR : (nj == 1) ? vA : vL;
                if (!vv) continue;
                const int px = q - nj;   // target output column

                // ni=0 -> output row a: neighbor rows {a, a+1}
                if (a <= H_T - 1)
                    upd(p[a][px], mc[a][px], c,
                        s[nj][1] + s[nj][2] + ((nj == 1) ? corr3 : corr5));
                // ni=1 -> output row a-1: neighbor rows {a-1, a, a+1}
                if (a >= 1 && a <= H_T)
                    upd(p[a - 1][px], mc[a - 1][px], c,
                        s[nj][0] + s[nj][1] + s[nj][2] + ((nj == 1) ? -1 : corr3));
                // ni=2 -> output row a-2: neighbor rows {a-1, a}
                if (a >= 2)
                    upd(p[a - 2][px], mc[a - 2][px], c,
                        s[nj][0] + s[nj][1] + ((nj == 1) ? corr3 : corr5));
            }
        }

        // output row a-2 received its last update (ni=2) this iteration
        if (a >= 2) {
            const int r = a - 2;
            float4 oa, ob;
            oa.x = p[r][0]; oa.y = p[r][1]; oa.z = p[r][2]; oa.w = p[r][3];
            ob.x = p[r][4]; ob.y = p[r][5]; ob.z = p[r][6]; ob.w = p[r][7];
            *reinterpret_cast<float4*>(dst + r * 128)     = oa;
            *reinterpret_cast<float4*>(dst + r * 128 + 4) = ob;
        }
    }
}

extern "C" void kernel_launch(void* const* d_in, const int* in_sizes, int n_in,
                              void* d_out, int out_size, void* d_ws, size_t ws_size,
                              hipStream_t stream) {
    const float* x   = (const float*)d_in[0];
    float*       out = (float*)d_out;
    const int threads = 256;
    const int total_threads = out_size / (H_T * W_T);   // 262144
    const int blocks  = total_threads / threads;        // 1024
    regp_pool_kernel<<<blocks, threads, 0, stream>>>(x, out);
}